// Round 11
// baseline (488.666 us; speedup 1.0000x reference)
//
#include <hip/hip_runtime.h>
#include <math.h>

#define B_  256
#define H_  200
#define N_  64
#define D_  640
#define DT_ 256
#define NH_ 10
#define HD_ 64
#define MT_ 13   // 13 m-tiles of 16 cover 208 >= 200

typedef __attribute__((ext_vector_type(8))) short bf16x8;
typedef __attribute__((ext_vector_type(4))) float f32x4;

__device__ __forceinline__ float wave_reduce_sum(float v) {
    #pragma unroll
    for (int m = 32; m > 0; m >>= 1) v += __shfl_xor(v, m);
    return v;
}
__device__ __forceinline__ float wave_reduce_max(float v) {
    #pragma unroll
    for (int m = 32; m > 0; m >>= 1) v = fmaxf(v, __shfl_xor(v, m));
    return v;
}
__device__ __forceinline__ float red16_sum(float v) {   // reduce over lane&15 group
    #pragma unroll
    for (int m = 1; m < 16; m <<= 1) v += __shfl_xor(v, m);
    return v;
}
__device__ __forceinline__ float red16_max(float v) {
    #pragma unroll
    for (int m = 1; m < 16; m <<= 1) v = fmaxf(v, __shfl_xor(v, m));
    return v;
}
__device__ __forceinline__ short f2bf(float x) {   // RNE bf16
    unsigned u = __float_as_uint(x);
    unsigned r = (u + 0x7fffu + ((u >> 16) & 1u)) >> 16;
    return (short)r;
}
__device__ __forceinline__ float bf2f(short s) {
    return __uint_as_float(((unsigned)(unsigned short)s) << 16);
}
// LDS XOR swizzle for bf16 A tiles (row stride mult of 128B)
#define SWZ(row, byte) ((byte) ^ (((row) & 7) << 4))

__device__ __forceinline__ void gload_lds16(const void* g, void* lds) {
    __builtin_amdgcn_global_load_lds(
        (const __attribute__((address_space(1))) void*)g,
        (__attribute__((address_space(3))) void*)lds, 16, 0, 0);
}

__global__ __launch_bounds__(256) void convert_w(
    const float* __restrict__ src, short* __restrict__ dst, int n)
{
    for (int i = blockIdx.x * 256 + threadIdx.x; i < n; i += gridDim.x * 256)
        dst[i] = f2bf(src[i]);
}

// Gate weight -> bf16 in K64-CHUNKED + PRE-SWIZZLED layout.
// chunk kc holds cols 0..639 x k in [kc*64, kc*64+64). 16B-granule index
// within a chunk: granule = (col*8 + ks8) ^ (col&7), ks8 = kk*4 + g where
// k_local = kk*32 + g*8 + elem. Linear global_load_lds staging then yields
// a 2-way-max bank pattern on the bf16x8 reads.
__global__ __launch_bounds__(256) void convert_wg(
    const float* __restrict__ src, short* __restrict__ dst)
{
    for (int i = blockIdx.x * 256 + threadIdx.x; i < D_ * D_; i += gridDim.x * 256) {
        const int col = i / D_, k = i % D_;
        const int kc = k >> 6, k6 = k & 63;
        const int ks8 = ((k6 >> 5) << 2) | ((k6 & 31) >> 3);
        const int elem = k & 7;
        const int granule = ((col << 3) | ks8) ^ (col & 7);
        dst[(long)kc * (D_ * 64) + granule * 8 + elem] = f2bf(src[i]);
    }
}

// Y_bf16[row, d] = bf16( sum_k X[row,k]*W[d,k] + bias[d] );  K = DT_ = 256.
__global__ __launch_bounds__(512, 2) void proj_mfma(
    const float* __restrict__ X, const short* __restrict__ Wb,
    const float* __restrict__ bias, short* __restrict__ Y)
{
    __shared__ short A_lds[64 * DT_];   // 32 KB swizzled bf16
    const int t = threadIdx.x;
    const int lane = t & 63, w = t >> 6;
    const int r16 = lane & 15, g = lane >> 4;
    const long row0 = (long)blockIdx.x * 64;

    {
        const int srow = t >> 3, sc = t & 7;
        const float4* src = (const float4*)(X + (row0 + srow) * DT_) + sc;
        float4 sv[8];
        #pragma unroll
        for (int j = 0; j < 8; ++j) sv[j] = src[8 * j];
        #pragma unroll
        for (int j = 0; j < 8; ++j) {
            short4 s;
            s.x = f2bf(sv[j].x); s.y = f2bf(sv[j].y);
            s.z = f2bf(sv[j].z); s.w = f2bf(sv[j].w);
            *(short4*)((char*)A_lds + SWZ(srow, srow * (DT_ * 2) + (sc + 8 * j) * 8)) = s;
        }
    }
    __syncthreads();

    f32x4 acc[5][4];
    #pragma unroll
    for (int ct = 0; ct < 5; ++ct)
        #pragma unroll
        for (int rt = 0; rt < 4; ++rt) acc[ct][rt] = (f32x4){0.f,0.f,0.f,0.f};

    const short* Wbase = Wb + (long)(w * 80 + r16) * DT_ + g * 8;

    bf16x8 aA[4], bA[5], aB[4], bB[5];
    #pragma unroll
    for (int rt = 0; rt < 4; ++rt) {
        const int row = rt * 16 + r16;
        aA[rt] = *(const bf16x8*)((const char*)A_lds + SWZ(row, row * (DT_ * 2) + g * 16));
    }
    #pragma unroll
    for (int ct = 0; ct < 5; ++ct) bA[ct] = *(const bf16x8*)(Wbase + ct * 16 * DT_);

    #pragma unroll
    for (int kc = 0; kc < 8; kc += 2) {
        {
            const int kn = kc + 1;
            #pragma unroll
            for (int rt = 0; rt < 4; ++rt) {
                const int row = rt * 16 + r16;
                aB[rt] = *(const bf16x8*)((const char*)A_lds +
                          SWZ(row, row * (DT_ * 2) + kn * 64 + g * 16));
            }
            #pragma unroll
            for (int ct = 0; ct < 5; ++ct)
                bB[ct] = *(const bf16x8*)(Wbase + ct * 16 * DT_ + kn * 32);
        }
        #pragma unroll
        for (int ct = 0; ct < 5; ++ct)
            #pragma unroll
            for (int rt = 0; rt < 4; ++rt)
                acc[ct][rt] = __builtin_amdgcn_mfma_f32_16x16x32_bf16(
                                  aA[rt], bA[ct], acc[ct][rt], 0, 0, 0);
        {
            const int kn = (kc + 2 < 8) ? kc + 2 : 0;
            #pragma unroll
            for (int rt = 0; rt < 4; ++rt) {
                const int row = rt * 16 + r16;
                aA[rt] = *(const bf16x8*)((const char*)A_lds +
                          SWZ(row, row * (DT_ * 2) + kn * 64 + g * 16));
            }
            #pragma unroll
            for (int ct = 0; ct < 5; ++ct)
                bA[ct] = *(const bf16x8*)(Wbase + ct * 16 * DT_ + kn * 32);
        }
        #pragma unroll
        for (int ct = 0; ct < 5; ++ct)
            #pragma unroll
            for (int rt = 0; rt < 4; ++rt)
                acc[ct][rt] = __builtin_amdgcn_mfma_f32_16x16x32_bf16(
                                  aB[rt], bB[ct], acc[ct][rt], 0, 0, 0);
    }

    #pragma unroll
    for (int ct = 0; ct < 5; ++ct) {
        const int col = w * 80 + ct * 16 + r16;
        const float bv = bias[col];
        #pragma unroll
        for (int rt = 0; rt < 4; ++rt)
            #pragma unroll
            for (int i = 0; i < 4; ++i)
                Y[(row0 + rt * 16 + g * 4 + i) * (long)D_ + col] =
                    f2bf(acc[ct][rt][i] + bv);
    }
}

// Fused attention + aggregation, one batch b per block.
__global__ __launch_bounds__(512, 2) void attn2(
    const short* __restrict__ Qb, const short* __restrict__ Kb,
    float* __restrict__ aw, float* __restrict__ out_tail)
{
    __shared__ float qn_l[N_];
    __shared__ float qw_l[N_];
    __shared__ float aggp[8][MT_ * 16];
    __shared__ float red2[2];
    const int t = threadIdx.x;
    const int lane = t & 63, w = t >> 6;
    const int wm = w & 3, hh = w >> 2;
    const int r16 = lane & 15, g = lane >> 4;
    const int b = blockIdx.x;

    if (hh == 0) {
        const short* qrow = Qb + ((long)(b * N_ + wm * 16 + r16)) * D_ + g * 160;
        float ss = 0.f;
        #pragma unroll
        for (int j = 0; j < 20; ++j) {
            bf16x8 v = *(const bf16x8*)(qrow + j * 8);
            #pragma unroll
            for (int e = 0; e < 8; ++e) { float f = bf2f(v[e]); ss += f * f; }
        }
        ss += __shfl_xor(ss, 16);
        ss += __shfl_xor(ss, 32);
        if (g == 0) qn_l[wm * 16 + r16] = ss;
    }
    __syncthreads();
    if (w == 0) {
        float v = sqrtf(qn_l[lane]);
        float mx = wave_reduce_max(v);
        float e = __expf(v - mx);
        float s = wave_reduce_sum(e);
        qw_l[lane] = e / s;
    }
    __syncthreads();

    float qwr[4];
    #pragma unroll
    for (int i = 0; i < 4; ++i) qwr[i] = qw_l[wm * 16 + g * 4 + i];

    const float inv_scale = 0.0395284707521047f;   // 1/sqrt(640)
    float aggl[MT_];
    #pragma unroll
    for (int mt = 0; mt < MT_; ++mt) aggl[mt] = 0.f;

    for (int hi = 0; hi < 5; ++hi) {
        const int h = hh * 5 + hi;
        const short* qbase = Qb + ((long)(b * N_ + wm * 16 + r16)) * D_ + h * HD_ + g * 8;
        bf16x8 a0 = *(const bf16x8*)(qbase);
        bf16x8 a1 = *(const bf16x8*)(qbase + 32);
        bf16x8 kb0[MT_], kb1[MT_];
        #pragma unroll
        for (int mt = 0; mt < MT_; ++mt) {
            const short* kbase = Kb + ((long)(b * H_ + mt * 16 + r16)) * D_ + h * HD_ + g * 8;
            kb0[mt] = *(const bf16x8*)(kbase);
            kb1[mt] = *(const bf16x8*)(kbase + 32);
        }
        f32x4 acc[MT_];
        #pragma unroll
        for (int mt = 0; mt < MT_; ++mt) {
            f32x4 z = {0.f,0.f,0.f,0.f};
            z = __builtin_amdgcn_mfma_f32_16x16x32_bf16(a0, kb0[mt], z, 0, 0, 0);
            z = __builtin_amdgcn_mfma_f32_16x16x32_bf16(a1, kb1[mt], z, 0, 0, 0);
            acc[mt] = z;
        }
        const bool tailok = (r16 < 8);
        float mx[4] = {-INFINITY, -INFINITY, -INFINITY, -INFINITY};
        #pragma unroll
        for (int mt = 0; mt < MT_; ++mt) {
            const bool valid = (mt < 12) || tailok;
            #pragma unroll
            for (int i = 0; i < 4; ++i)
                if (valid) mx[i] = fmaxf(mx[i], acc[mt][i]);
        }
        #pragma unroll
        for (int i = 0; i < 4; ++i) mx[i] = red16_max(mx[i]);
        float sum[4] = {0.f, 0.f, 0.f, 0.f};
        #pragma unroll
        for (int mt = 0; mt < MT_; ++mt) {
            const bool valid = (mt < 12) || tailok;
            #pragma unroll
            for (int i = 0; i < 4; ++i) {
                float e = valid ? __expf((acc[mt][i] - mx[i]) * inv_scale) : 0.f;
                acc[mt][i] = e;
                sum[i] += e;
            }
        }
        float fct[4];
        #pragma unroll
        for (int i = 0; i < 4; ++i) fct[i] = qwr[i] / red16_sum(sum[i]);
        #pragma unroll
        for (int mt = 0; mt < MT_; ++mt)
            aggl[mt] += acc[mt][0] * fct[0] + acc[mt][1] * fct[1]
                      + acc[mt][2] * fct[2] + acc[mt][3] * fct[3];
    }
    #pragma unroll
    for (int mt = 0; mt < MT_; ++mt) {
        aggl[mt] += __shfl_xor(aggl[mt], 16);
        aggl[mt] += __shfl_xor(aggl[mt], 32);
    }
    if (g == 0) {
        #pragma unroll
        for (int mt = 0; mt < MT_; ++mt) aggp[w][mt * 16 + r16] = aggl[mt];
    }
    __syncthreads();
    if (t < MT_ * 16) {
        float v = 0.f;
        #pragma unroll
        for (int j = 0; j < 8; ++j) v += aggp[j][t];
        aggp[0][t] = v;
    }
    __syncthreads();
    if (w == 0) {
        float v0 = aggp[0][lane], v1 = aggp[0][lane + 64], v2 = aggp[0][lane + 128];
        const bool has3 = lane < (H_ - 192);
        float v3 = has3 ? aggp[0][lane + 192] : -INFINITY;
        float mx = wave_reduce_max(fmaxf(fmaxf(v0, v1), fmaxf(v2, v3)));
        float s = __expf(v0 - mx) + __expf(v1 - mx) + __expf(v2 - mx)
                + (has3 ? __expf(v3 - mx) : 0.f);
        s = wave_reduce_sum(s);
        if (lane == 0) { red2[0] = mx; red2[1] = s; }
    }
    __syncthreads();
    if (t < H_) {
        float v = __expf(aggp[0][t] - red2[0]) / red2[1];
        aw[b * H_ + t] = v;
        out_tail[b * H_ + t] = v;
    }
}

// gate GEMM + blend + LayerNorm, v7: few fat chunks.
// BM=128, BN=640, 1024 threads = 16 waves (2 M-halves x 8 col-strips of 80).
// Wave tile 64x80 -> acc[5][4]. K-chunk 64 -> 10 chunks, 40 MFMA/wave/chunk.
// W-chunk 80 KB + A-chunk fp32 32 KB staged via global_load_lds; 2 barriers
// per chunk. Drains per CU: 400 blocks/256 x 10 = 15.6 (vs 125 in r9/r10).
// LN via reused W_lds scratch. launch_bounds(1024,4) -> all 16 waves resident.
__global__ __launch_bounds__(1024, 4) void out_mfma(
    const float* __restrict__ clicked, const float* __restrict__ aw,
    const short* __restrict__ Wgb, const float* __restrict__ bg,
    const float* __restrict__ gamma, const float* __restrict__ beta,
    float* __restrict__ out)
{
    __shared__ short W_lds[D_ * 64];     // 80 KB, pre-swizzled chunk layout
    __shared__ float A_f[128 * 64];      // 32 KB fp32 A chunk (swizzled slots)
    const int t = threadIdx.x;
    const int lane = t & 63, w = t >> 6;         // w 0..15
    const int wm = w >> 3, wn = w & 7;           // M-half, col-strip
    const int r16 = lane & 15, g = lane >> 4;
    const int bid = blockIdx.x;
    const long row0 = (long)bid * 128;

    f32x4 acc[5][4];
    #pragma unroll
    for (int ct = 0; ct < 5; ++ct)
        #pragma unroll
        for (int rt = 0; rt < 4; ++rt) acc[ct][rt] = (f32x4){0.f,0.f,0.f,0.f};

    // A staging: granules G0 = t (rows 0..63), G1 = t+1024 (rows 64..127).
    // Granule G: row = G>>4, slot j = G&15, source floats = clicked[row0+row]
    // [k*64 + (j^(row&7))*4 ..+3]  (inverse swizzle on the SOURCE, rule 21).
    const int a_row0 = t >> 4,        a_j0 = t & 15;
    const int a_row1 = (t >> 4) + 64, a_j1 = t & 15;
    const float* Ag0 = clicked + (row0 + a_row0) * (long)D_ + ((a_j0 ^ (a_row0 & 7)) << 2);
    const float* Ag1 = clicked + (row0 + a_row1) * (long)D_ + ((a_j1 ^ (a_row1 & 7)) << 2);

    for (int k = 0; k < 10; ++k) {
        // stage W chunk k: 5120 granules, 5 per thread, linear
        {
            const short* wsrc = Wgb + (long)k * (D_ * 64);
            #pragma unroll
            for (int j = 0; j < 5; ++j) {
                const int u = t + j * 1024;
                gload_lds16(wsrc + u * 8, (char*)W_lds + u * 16);
            }
        }
        // stage A chunk k: 2048 granules, 2 per thread
        gload_lds16(Ag0 + k * 64, (char*)A_f + t * 16);
        gload_lds16(Ag1 + k * 64, (char*)A_f + (t + 1024) * 16);
        __syncthreads();   // drain all gloads

        // compute: 2 kk-steps x (4 A-frags convert + 5 B-frags x 4 MFMA)
        #pragma unroll
        for (int kk = 0; kk < 2; ++kk) {
            bf16x8 a[4];
            #pragma unroll
            for (int rt = 0; rt < 4; ++rt) {
                const int row = wm * 64 + rt * 16 + r16;
                const int j0 = kk * 8 + g * 2;
                float4 f0 = *(const float4*)((const char*)A_f +
                             row * 256 + ((j0 ^ (row & 7)) << 4));
                float4 f1 = *(const float4*)((const char*)A_f +
                             row * 256 + (((j0 + 1) ^ (row & 7)) << 4));
                bf16x8 av;
                av[0] = f2bf(f0.x); av[1] = f2bf(f0.y); av[2] = f2bf(f0.z); av[3] = f2bf(f0.w);
                av[4] = f2bf(f1.x); av[5] = f2bf(f1.y); av[6] = f2bf(f1.z); av[7] = f2bf(f1.w);
                a[rt] = av;
            }
            #pragma unroll
            for (int ct = 0; ct < 5; ++ct) {
                const int col = wn * 80 + ct * 16 + r16;
                const int granule = ((col << 3) | (kk * 4 + g)) ^ (col & 7);
                bf16x8 bb = *(const bf16x8*)((const char*)W_lds + granule * 16);
                #pragma unroll
                for (int rt = 0; rt < 4; ++rt)
                    acc[ct][rt] = __builtin_amdgcn_mfma_f32_16x16x32_bf16(
                                      a[rt], bb, acc[ct][rt], 0, 0, 0);
            }
        }
        __syncthreads();   // done reading W_lds/A_f -> safe to overwrite
    }

    // ---- epilogue: z = aw*y + bg; gate; o = cl*(1 + gt*(aw-1)); LN ----
    float awv[4][4];
    #pragma unroll
    for (int rt = 0; rt < 4; ++rt)
        #pragma unroll
        for (int i = 0; i < 4; ++i)
            awv[rt][i] = aw[row0 + wm * 64 + rt * 16 + g * 4 + i];

    float ps[4][4], pq[4][4];
    #pragma unroll
    for (int rt = 0; rt < 4; ++rt)
        #pragma unroll
        for (int i = 0; i < 4; ++i) { ps[rt][i] = 0.f; pq[rt][i] = 0.f; }

    #pragma unroll
    for (int ct = 0; ct < 5; ++ct) {
        const int col = wn * 80 + ct * 16 + r16;
        const float bgv = bg[col];
        #pragma unroll
        for (int rt = 0; rt < 4; ++rt)
            #pragma unroll
            for (int i = 0; i < 4; ++i) {
                const int row = wm * 64 + rt * 16 + g * 4 + i;
                const float awr = awv[rt][i];
                const float cl = clicked[(row0 + row) * (long)D_ + col];
                const float z  = awr * acc[ct][rt][i] + bgv;
                const float gt = 1.f / (1.f + __expf(-z));
                const float o  = cl * (1.f + gt * (awr - 1.f));
                acc[ct][rt][i] = o;
                ps[rt][i] += o; pq[rt][i] += o * o;
            }
    }
    // cross-wave LN partials in reused W_lds (as float scratch)
    float* scr = (float*)W_lds;          // part[128][8][2] = 8 KB; mu/ri at 2048
    #pragma unroll
    for (int rt = 0; rt < 4; ++rt)
        #pragma unroll
        for (int i = 0; i < 4; ++i) {
            const float s  = red16_sum(ps[rt][i]);
            const float sq = red16_sum(pq[rt][i]);
            if (r16 == 0) {
                const int row = wm * 64 + rt * 16 + g * 4 + i;
                scr[(row * 8 + wn) * 2 + 0] = s;
                scr[(row * 8 + wn) * 2 + 1] = sq;
            }
        }
    __syncthreads();
    if (t < 128) {
        float s = 0.f, q = 0.f;
        #pragma unroll
        for (int j = 0; j < 8; ++j) {
            s += scr[(t * 8 + j) * 2 + 0];
            q += scr[(t * 8 + j) * 2 + 1];
        }
        const float m = s * (1.f / D_);
        const float v = q * (1.f / D_) - m * m;
        scr[2048 + t * 2 + 0] = m;
        scr[2048 + t * 2 + 1] = 1.0f / sqrtf(v + 1e-5f);
    }
    __syncthreads();

    #pragma unroll
    for (int rt = 0; rt < 4; ++rt)
        #pragma unroll
        for (int i = 0; i < 4; ++i) {
            const int row = wm * 64 + rt * 16 + g * 4 + i;
            const float mu = scr[2048 + row * 2 + 0];
            const float ri = scr[2048 + row * 2 + 1];
            #pragma unroll
            for (int ct = 0; ct < 5; ++ct) {
                const int col = wn * 80 + ct * 16 + r16;
                out[(row0 + row) * (long)D_ + col] =
                    (acc[ct][rt][i] - mu) * ri * gamma[col] + beta[col];
            }
        }
}

extern "C" void kernel_launch(void* const* d_in, const int* in_sizes, int n_in,
                              void* d_out, int out_size, void* d_ws, size_t ws_size,
                              hipStream_t stream) {
    const float* clicked_news   = (const float*)d_in[0];   // [B,H,D]
    const float* clicked_topics = (const float*)d_in[1];   // [B,H,Dt]
    const float* cand_topics    = (const float*)d_in[2];   // [B,N,Dt]
    const float* Wq = (const float*)d_in[3];
    const float* bq = (const float*)d_in[4];
    const float* Wk = (const float*)d_in[5];
    const float* bk = (const float*)d_in[6];
    // d_in[7], d_in[8] = Wv, bv: dead code w.r.t. outputs
    const float* Wg = (const float*)d_in[9];
    const float* bg = (const float*)d_in[10];
    const float* ln_gamma = (const float*)d_in[11];
    const float* ln_beta  = (const float*)d_in[12];

    float* out = (float*)d_out;
    float* ws  = (float*)d_ws;

    // ws layout: aw (f32), then bf16 arrays
    float* aw     = ws;                                  // B*H floats
    short* sbase  = (short*)(aw + (long)B_ * H_);
    short* Qb   = sbase;                                 // B*N*D shorts
    short* Wq_b = Qb + (long)B_ * N_ * D_;               // 163,840
    short* Wg_b = Wq_b + (long)D_ * DT_;                 // 409,600 (chunked+swz)
    short* Wk_b = Wg_b + (long)D_ * D_;                  // 163,840
    // Kb (bf16) at start of d_out: read by attn2, overwritten by out_mfma.
    short* Kb = (short*)d_out;
    float* out_tail = out + (long)B_ * H_ * D_;          // attn_weights_agg

    convert_w<<<128, 256, 0, stream>>>(Wq, Wq_b, D_ * DT_);
    convert_w<<<128, 256, 0, stream>>>(Wk, Wk_b, D_ * DT_);
    convert_wg<<<256, 256, 0, stream>>>(Wg, Wg_b);

    proj_mfma<<<(B_ * N_) / 64, 512, 0, stream>>>(cand_topics, Wq_b, bq, Qb);
    proj_mfma<<<(B_ * H_) / 64, 512, 0, stream>>>(clicked_topics, Wk_b, bk, Kb);
    attn2<<<B_, 512, 0, stream>>>(Qb, Kb, aw, out_tail);
    out_mfma<<<(B_ * H_) / 128, 1024, 0, stream>>>(clicked_news, aw, Wg_b, bg,
                                                   ln_gamma, ln_beta, out);
}

// Round 12
// 333.623 us; speedup vs baseline: 1.4647x; 1.4647x over previous
//
#include <hip/hip_runtime.h>
#include <math.h>

#define B_  256
#define H_  200
#define N_  64
#define D_  640
#define DT_ 256
#define NH_ 10
#define HD_ 64
#define MT_ 13   // 13 m-tiles of 16 cover 208 >= 200
#define MH_ 25600  // M half (B_*H_/2)

typedef __attribute__((ext_vector_type(8))) short bf16x8;
typedef __attribute__((ext_vector_type(4))) float f32x4;

__device__ __forceinline__ float wave_reduce_sum(float v) {
    #pragma unroll
    for (int m = 32; m > 0; m >>= 1) v += __shfl_xor(v, m);
    return v;
}
__device__ __forceinline__ float wave_reduce_max(float v) {
    #pragma unroll
    for (int m = 32; m > 0; m >>= 1) v = fmaxf(v, __shfl_xor(v, m));
    return v;
}
__device__ __forceinline__ float red16_sum(float v) {   // reduce over lane&15 group
    #pragma unroll
    for (int m = 1; m < 16; m <<= 1) v += __shfl_xor(v, m);
    return v;
}
__device__ __forceinline__ float red16_max(float v) {
    #pragma unroll
    for (int m = 1; m < 16; m <<= 1) v = fmaxf(v, __shfl_xor(v, m));
    return v;
}
__device__ __forceinline__ short f2bf(float x) {   // RNE bf16
    unsigned u = __float_as_uint(x);
    unsigned r = (u + 0x7fffu + ((u >> 16) & 1u)) >> 16;
    return (short)r;
}
__device__ __forceinline__ float bf2f(short s) {
    return __uint_as_float(((unsigned)(unsigned short)s) << 16);
}
// LDS XOR swizzle for bf16 A tiles (row stride mult of 128B) - proj kernel
#define SWZ(row, byte) ((byte) ^ (((row) & 7) << 4))

__device__ __forceinline__ void gload_lds16(const void* g, void* lds) {
    __builtin_amdgcn_global_load_lds(
        (const __attribute__((address_space(1))) void*)g,
        (__attribute__((address_space(3))) void*)lds, 16, 0, 0);
}

__global__ __launch_bounds__(256) void convert_w(
    const float* __restrict__ src, short* __restrict__ dst, int n)
{
    for (int i = blockIdx.x * 256 + threadIdx.x; i < n; i += gridDim.x * 256)
        dst[i] = f2bf(src[i]);
}

// Y_bf16[row, d] = bf16( sum_k X[row,k]*W[d,k] + bias[d] );  K = DT_ = 256.
__global__ __launch_bounds__(512, 2) void proj_mfma(
    const float* __restrict__ X, const short* __restrict__ Wb,
    const float* __restrict__ bias, short* __restrict__ Y)
{
    __shared__ short A_lds[64 * DT_];   // 32 KB swizzled bf16
    const int t = threadIdx.x;
    const int lane = t & 63, w = t >> 6;
    const int r16 = lane & 15, g = lane >> 4;
    const long row0 = (long)blockIdx.x * 64;

    {
        const int srow = t >> 3, sc = t & 7;
        const float4* src = (const float4*)(X + (row0 + srow) * DT_) + sc;
        float4 sv[8];
        #pragma unroll
        for (int j = 0; j < 8; ++j) sv[j] = src[8 * j];
        #pragma unroll
        for (int j = 0; j < 8; ++j) {
            short4 s;
            s.x = f2bf(sv[j].x); s.y = f2bf(sv[j].y);
            s.z = f2bf(sv[j].z); s.w = f2bf(sv[j].w);
            *(short4*)((char*)A_lds + SWZ(srow, srow * (DT_ * 2) + (sc + 8 * j) * 8)) = s;
        }
    }
    __syncthreads();

    f32x4 acc[5][4];
    #pragma unroll
    for (int ct = 0; ct < 5; ++ct)
        #pragma unroll
        for (int rt = 0; rt < 4; ++rt) acc[ct][rt] = (f32x4){0.f,0.f,0.f,0.f};

    const short* Wbase = Wb + (long)(w * 80 + r16) * DT_ + g * 8;

    bf16x8 aA[4], bA[5], aB[4], bB[5];
    #pragma unroll
    for (int rt = 0; rt < 4; ++rt) {
        const int row = rt * 16 + r16;
        aA[rt] = *(const bf16x8*)((const char*)A_lds + SWZ(row, row * (DT_ * 2) + g * 16));
    }
    #pragma unroll
    for (int ct = 0; ct < 5; ++ct) bA[ct] = *(const bf16x8*)(Wbase + ct * 16 * DT_);

    #pragma unroll
    for (int kc = 0; kc < 8; kc += 2) {
        {
            const int kn = kc + 1;
            #pragma unroll
            for (int rt = 0; rt < 4; ++rt) {
                const int row = rt * 16 + r16;
                aB[rt] = *(const bf16x8*)((const char*)A_lds +
                          SWZ(row, row * (DT_ * 2) + kn * 64 + g * 16));
            }
            #pragma unroll
            for (int ct = 0; ct < 5; ++ct)
                bB[ct] = *(const bf16x8*)(Wbase + ct * 16 * DT_ + kn * 32);
        }
        #pragma unroll
        for (int ct = 0; ct < 5; ++ct)
            #pragma unroll
            for (int rt = 0; rt < 4; ++rt)
                acc[ct][rt] = __builtin_amdgcn_mfma_f32_16x16x32_bf16(
                                  aA[rt], bA[ct], acc[ct][rt], 0, 0, 0);
        {
            const int kn = (kc + 2 < 8) ? kc + 2 : 0;
            #pragma unroll
            for (int rt = 0; rt < 4; ++rt) {
                const int row = rt * 16 + r16;
                aA[rt] = *(const bf16x8*)((const char*)A_lds +
                          SWZ(row, row * (DT_ * 2) + kn * 64 + g * 16));
            }
            #pragma unroll
            for (int ct = 0; ct < 5; ++ct)
                bA[ct] = *(const bf16x8*)(Wbase + ct * 16 * DT_ + kn * 32);
        }
        #pragma unroll
        for (int ct = 0; ct < 5; ++ct)
            #pragma unroll
            for (int rt = 0; rt < 4; ++rt)
                acc[ct][rt] = __builtin_amdgcn_mfma_f32_16x16x32_bf16(
                                  aB[rt], bB[ct], acc[ct][rt], 0, 0, 0);
    }

    #pragma unroll
    for (int ct = 0; ct < 5; ++ct) {
        const int col = w * 80 + ct * 16 + r16;
        const float bv = bias[col];
        #pragma unroll
        for (int rt = 0; rt < 4; ++rt)
            #pragma unroll
            for (int i = 0; i < 4; ++i)
                Y[(row0 + rt * 16 + g * 4 + i) * (long)D_ + col] =
                    f2bf(acc[ct][rt][i] + bv);
    }
}

// Fused attention + aggregation, one batch b per block.
__global__ __launch_bounds__(512, 2) void attn2(
    const short* __restrict__ Qb, const short* __restrict__ Kb,
    float* __restrict__ aw, float* __restrict__ out_tail)
{
    __shared__ float qn_l[N_];
    __shared__ float qw_l[N_];
    __shared__ float aggp[8][MT_ * 16];
    __shared__ float red2[2];
    const int t = threadIdx.x;
    const int lane = t & 63, w = t >> 6;
    const int wm = w & 3, hh = w >> 2;
    const int r16 = lane & 15, g = lane >> 4;
    const int b = blockIdx.x;

    if (hh == 0) {
        const short* qrow = Qb + ((long)(b * N_ + wm * 16 + r16)) * D_ + g * 160;
        float ss = 0.f;
        #pragma unroll
        for (int j = 0; j < 20; ++j) {
            bf16x8 v = *(const bf16x8*)(qrow + j * 8);
            #pragma unroll
            for (int e = 0; e < 8; ++e) { float f = bf2f(v[e]); ss += f * f; }
        }
        ss += __shfl_xor(ss, 16);
        ss += __shfl_xor(ss, 32);
        if (g == 0) qn_l[wm * 16 + r16] = ss;
    }
    __syncthreads();
    if (w == 0) {
        float v = sqrtf(qn_l[lane]);
        float mx = wave_reduce_max(v);
        float e = __expf(v - mx);
        float s = wave_reduce_sum(e);
        qw_l[lane] = e / s;
    }
    __syncthreads();

    float qwr[4];
    #pragma unroll
    for (int i = 0; i < 4; ++i) qwr[i] = qw_l[wm * 16 + g * 4 + i];

    const float inv_scale = 0.0395284707521047f;   // 1/sqrt(640)
    float aggl[MT_];
    #pragma unroll
    for (int mt = 0; mt < MT_; ++mt) aggl[mt] = 0.f;

    for (int hi = 0; hi < 5; ++hi) {
        const int h = hh * 5 + hi;
        const short* qbase = Qb + ((long)(b * N_ + wm * 16 + r16)) * D_ + h * HD_ + g * 8;
        bf16x8 a0 = *(const bf16x8*)(qbase);
        bf16x8 a1 = *(const bf16x8*)(qbase + 32);
        bf16x8 kb0[MT_], kb1[MT_];
        #pragma unroll
        for (int mt = 0; mt < MT_; ++mt) {
            const short* kbase = Kb + ((long)(b * H_ + mt * 16 + r16)) * D_ + h * HD_ + g * 8;
            kb0[mt] = *(const bf16x8*)(kbase);
            kb1[mt] = *(const bf16x8*)(kbase + 32);
        }
        f32x4 acc[MT_];
        #pragma unroll
        for (int mt = 0; mt < MT_; ++mt) {
            f32x4 z = {0.f,0.f,0.f,0.f};
            z = __builtin_amdgcn_mfma_f32_16x16x32_bf16(a0, kb0[mt], z, 0, 0, 0);
            z = __builtin_amdgcn_mfma_f32_16x16x32_bf16(a1, kb1[mt], z, 0, 0, 0);
            acc[mt] = z;
        }
        const bool tailok = (r16 < 8);
        float mx[4] = {-INFINITY, -INFINITY, -INFINITY, -INFINITY};
        #pragma unroll
        for (int mt = 0; mt < MT_; ++mt) {
            const bool valid = (mt < 12) || tailok;
            #pragma unroll
            for (int i = 0; i < 4; ++i)
                if (valid) mx[i] = fmaxf(mx[i], acc[mt][i]);
        }
        #pragma unroll
        for (int i = 0; i < 4; ++i) mx[i] = red16_max(mx[i]);
        float sum[4] = {0.f, 0.f, 0.f, 0.f};
        #pragma unroll
        for (int mt = 0; mt < MT_; ++mt) {
            const bool valid = (mt < 12) || tailok;
            #pragma unroll
            for (int i = 0; i < 4; ++i) {
                float e = valid ? __expf((acc[mt][i] - mx[i]) * inv_scale) : 0.f;
                acc[mt][i] = e;
                sum[i] += e;
            }
        }
        float fct[4];
        #pragma unroll
        for (int i = 0; i < 4; ++i) fct[i] = qwr[i] / red16_sum(sum[i]);
        #pragma unroll
        for (int mt = 0; mt < MT_; ++mt)
            aggl[mt] += acc[mt][0] * fct[0] + acc[mt][1] * fct[1]
                      + acc[mt][2] * fct[2] + acc[mt][3] * fct[3];
    }
    #pragma unroll
    for (int mt = 0; mt < MT_; ++mt) {
        aggl[mt] += __shfl_xor(aggl[mt], 16);
        aggl[mt] += __shfl_xor(aggl[mt], 32);
    }
    if (g == 0) {
        #pragma unroll
        for (int mt = 0; mt < MT_; ++mt) aggp[w][mt * 16 + r16] = aggl[mt];
    }
    __syncthreads();
    if (t < MT_ * 16) {
        float v = 0.f;
        #pragma unroll
        for (int j = 0; j < 8; ++j) v += aggp[j][t];
        aggp[0][t] = v;
    }
    __syncthreads();
    if (w == 0) {
        float v0 = aggp[0][lane], v1 = aggp[0][lane + 64], v2 = aggp[0][lane + 128];
        const bool has3 = lane < (H_ - 192);
        float v3 = has3 ? aggp[0][lane + 192] : -INFINITY;
        float mx = wave_reduce_max(fmaxf(fmaxf(v0, v1), fmaxf(v2, v3)));
        float s = __expf(v0 - mx) + __expf(v1 - mx) + __expf(v2 - mx)
                + (has3 ? __expf(v3 - mx) : 0.f);
        s = wave_reduce_sum(s);
        if (lane == 0) { red2[0] = mx; red2[1] = s; }
    }
    __syncthreads();
    if (t < H_) {
        float v = __expf(aggp[0][t] - red2[0]) / red2[1];
        aw[b * H_ + t] = v;
        out_tail[b * H_ + t] = v;
    }
}

// zgemm: Y[row,col] = sum_k A[row,k] * Wg[col,k]  (bf16 out, no bias/aw).
// m97 geometry: BM=128, BN=128, BK=64, 256 threads = 4 waves (2x2).
// A fp32 staged via global_load_lds (32 KB, linear), converted at frag-read;
// B bf16 row-major [col][k] staged via global_load_lds (16 KB, linear).
// Linear LDS (no swizzle): T2 is null at 2-phase (regime table).
// Grid: (rows/128) x 5 col-strips, col fastest (A-panel L2/L3 reuse).
__global__ __launch_bounds__(256, 3) void zgemm(
    const float* __restrict__ A, const short* __restrict__ Wb,
    short* __restrict__ Z)
{
    __shared__ float A_f[128 * 64];     // 32 KB fp32 [row][k]
    __shared__ short B_lds[128 * 64];   // 16 KB bf16 [col][k]
    const int t = threadIdx.x;
    const int lane = t & 63, w = t >> 6;
    const int wm = w >> 1, wn = w & 1;
    const int r16 = lane & 15, g = lane >> 4;
    const int row0 = (blockIdx.x / 5) * 128;
    const int col0 = (blockIdx.x % 5) * 128;

    f32x4 acc[4][4];
    #pragma unroll
    for (int ct = 0; ct < 4; ++ct)
        #pragma unroll
        for (int rt = 0; rt < 4; ++rt) acc[ct][rt] = (f32x4){0.f,0.f,0.f,0.f};

    for (int k = 0; k < 10; ++k) {
        const int k0 = k * 64;
        // stage A: 2048 granules (16B = 4 floats), 8/thread, linear
        #pragma unroll
        for (int j = 0; j < 8; ++j) {
            const int u = t + j * 256;
            const int row = u >> 4, gr = u & 15;
            gload_lds16(A + (long)(row0 + row) * D_ + k0 + gr * 4,
                        (char*)A_f + u * 16);
        }
        // stage B: 1024 granules (16B = 8 bf16), 4/thread, linear
        #pragma unroll
        for (int j = 0; j < 4; ++j) {
            const int u = t + j * 256;
            const int col = u >> 3, gr = u & 7;
            gload_lds16(Wb + (long)(col0 + col) * D_ + k0 + gr * 8,
                        (char*)B_lds + u * 16);
        }
        __syncthreads();

        #pragma unroll
        for (int kk = 0; kk < 2; ++kk) {
            bf16x8 a[4];
            #pragma unroll
            for (int rt = 0; rt < 4; ++rt) {
                const int row = wm * 64 + rt * 16 + r16;
                float4 f0 = *(const float4*)(A_f + row * 64 + kk * 32 + g * 8);
                float4 f1 = *(const float4*)(A_f + row * 64 + kk * 32 + g * 8 + 4);
                bf16x8 av;
                av[0] = f2bf(f0.x); av[1] = f2bf(f0.y); av[2] = f2bf(f0.z); av[3] = f2bf(f0.w);
                av[4] = f2bf(f1.x); av[5] = f2bf(f1.y); av[6] = f2bf(f1.z); av[7] = f2bf(f1.w);
                a[rt] = av;
            }
            bf16x8 b[4];
            #pragma unroll
            for (int ct = 0; ct < 4; ++ct) {
                const int col = wn * 64 + ct * 16 + r16;
                b[ct] = *(const bf16x8*)(B_lds + col * 64 + kk * 32 + g * 8);
            }
            #pragma unroll
            for (int ct = 0; ct < 4; ++ct)
                #pragma unroll
                for (int rt = 0; rt < 4; ++rt)
                    acc[ct][rt] = __builtin_amdgcn_mfma_f32_16x16x32_bf16(
                                      a[rt], b[ct], acc[ct][rt], 0, 0, 0);
        }
        __syncthreads();
    }

    // write Z bf16: C/D layout col = lane&15, row = g*4 + i
    #pragma unroll
    for (int ct = 0; ct < 4; ++ct) {
        const int col = col0 + wn * 64 + ct * 16 + r16;
        #pragma unroll
        for (int rt = 0; rt < 4; ++rt)
            #pragma unroll
            for (int i = 0; i < 4; ++i)
                Z[(long)(row0 + wm * 64 + rt * 16 + g * 4 + i) * D_ + col] =
                    f2bf(acc[ct][rt][i]);
    }
}

// blendln: z = aw*y + bg; gate = sigmoid(z); o = cl*(1 + gt*(aw-1)); LN.
// One wave per row; 4 rows per 256-thread block.
__global__ __launch_bounds__(256) void blendln(
    const float* __restrict__ cl, const short* __restrict__ Z,
    const float* __restrict__ aw, const float* __restrict__ bg,
    const float* __restrict__ gamma, const float* __restrict__ beta,
    float* __restrict__ out)
{
    const int t = threadIdx.x;
    const int lane = t & 63, w = t >> 6;
    const int row = blockIdx.x * 4 + w;
    const float awr = aw[row];
    const long base = (long)row * D_;

    float o[10];
    float s = 0.f, sq = 0.f;
    #pragma unroll
    for (int i = 0; i < 10; ++i) {
        const int col = lane + 64 * i;
        const float y = bf2f(Z[base + col]);
        const float c = cl[base + col];
        const float z = awr * y + bg[col];
        const float gt = 1.f / (1.f + __expf(-z));
        const float ov = c * (1.f + gt * (awr - 1.f));
        o[i] = ov; s += ov; sq += ov * ov;
    }
    s  = wave_reduce_sum(s);
    sq = wave_reduce_sum(sq);
    const float mu  = s * (1.f / D_);
    const float var = sq * (1.f / D_) - mu * mu;
    const float ri  = 1.0f / sqrtf(var + 1e-5f);
    #pragma unroll
    for (int i = 0; i < 10; ++i) {
        const int col = lane + 64 * i;
        out[base + col] = (o[i] - mu) * ri * gamma[col] + beta[col];
    }
}

extern "C" void kernel_launch(void* const* d_in, const int* in_sizes, int n_in,
                              void* d_out, int out_size, void* d_ws, size_t ws_size,
                              hipStream_t stream) {
    const float* clicked_news   = (const float*)d_in[0];   // [B,H,D]
    const float* clicked_topics = (const float*)d_in[1];   // [B,H,Dt]
    const float* cand_topics    = (const float*)d_in[2];   // [B,N,Dt]
    const float* Wq = (const float*)d_in[3];
    const float* bq = (const float*)d_in[4];
    const float* Wk = (const float*)d_in[5];
    const float* bk = (const float*)d_in[6];
    // d_in[7], d_in[8] = Wv, bv: dead code w.r.t. outputs
    const float* Wg = (const float*)d_in[9];
    const float* bg = (const float*)d_in[10];
    const float* ln_gamma = (const float*)d_in[11];
    const float* ln_beta  = (const float*)d_in[12];

    float* out = (float*)d_out;
    float* ws  = (float*)d_ws;

    // ws layout: aw, weights, then Qb; Z (bf16, half-M) ALIASES Qb (Qb is
    // dead after attn2; zgemm/blendln run after attn2 on the same stream).
    float* aw   = ws;                                    // B*H floats
    short* Wq_b = (short*)(aw + (long)B_ * H_);          // 163,840
    short* Wk_b = Wq_b + (long)D_ * DT_;                 // 163,840
    short* Wg_b = Wk_b + (long)D_ * DT_;                 // 409,600 row-major [col][k]
    short* Qb   = Wg_b + (long)D_ * D_;                  // 10,485,760
    short* Z    = Qb;                                    // 16,384,000 (overlaps Qb+)
    // Kb (bf16) at start of d_out: read by attn2, overwritten by blendln.
    short* Kb = (short*)d_out;
    float* out_tail = out + (long)B_ * H_ * D_;          // attn_weights_agg

    convert_w<<<128, 256, 0, stream>>>(Wq, Wq_b, D_ * DT_);
    convert_w<<<128, 256, 0, stream>>>(Wk, Wk_b, D_ * DT_);
    convert_w<<<256, 256, 0, stream>>>(Wg, Wg_b, D_ * D_);

    proj_mfma<<<(B_ * N_) / 64, 512, 0, stream>>>(cand_topics, Wq_b, bq, Qb);
    proj_mfma<<<(B_ * H_) / 64, 512, 0, stream>>>(clicked_topics, Wk_b, bk, Kb);
    attn2<<<B_, 512, 0, stream>>>(Qb, Kb, aw, out_tail);

    for (int h = 0; h < 2; ++h) {
        const long off = (long)h * MH_;
        zgemm<<<(MH_ / 128) * 5, 256, 0, stream>>>(
            clicked_news + off * D_, Wg_b, Z);
        blendln<<<MH_ / 4, 256, 0, stream>>>(
            clicked_news + off * D_, Z, aw + off, bg, ln_gamma, ln_beta,
            out + off * D_);
    }
}

// Round 13
// 300.042 us; speedup vs baseline: 1.6287x; 1.1119x over previous
//
#include <hip/hip_runtime.h>
#include <math.h>

#define B_  256
#define H_  200
#define N_  64
#define D_  640
#define DT_ 256
#define NH_ 10
#define HD_ 64
#define MT_ 13   // 13 m-tiles of 16 cover 208 >= 200
#define MH_ 25600  // M half (B_*H_/2)

typedef __attribute__((ext_vector_type(8))) short bf16x8;
typedef __attribute__((ext_vector_type(4))) float f32x4;

__device__ __forceinline__ float wave_reduce_sum(float v) {
    #pragma unroll
    for (int m = 32; m > 0; m >>= 1) v += __shfl_xor(v, m);
    return v;
}
__device__ __forceinline__ float wave_reduce_max(float v) {
    #pragma unroll
    for (int m = 32; m > 0; m >>= 1) v = fmaxf(v, __shfl_xor(v, m));
    return v;
}
__device__ __forceinline__ float red16_sum(float v) {   // reduce over lane&15 group
    #pragma unroll
    for (int m = 1; m < 16; m <<= 1) v += __shfl_xor(v, m);
    return v;
}
__device__ __forceinline__ float red16_max(float v) {
    #pragma unroll
    for (int m = 1; m < 16; m <<= 1) v = fmaxf(v, __shfl_xor(v, m));
    return v;
}
__device__ __forceinline__ short f2bf(float x) {   // RNE bf16
    unsigned u = __float_as_uint(x);
    unsigned r = (u + 0x7fffu + ((u >> 16) & 1u)) >> 16;
    return (short)r;
}
__device__ __forceinline__ float bf2f(short s) {
    return __uint_as_float(((unsigned)(unsigned short)s) << 16);
}
// LDS XOR swizzle for bf16 A tiles (row stride mult of 128B) - proj kernel
#define SWZ(row, byte) ((byte) ^ (((row) & 7) << 4))

__device__ __forceinline__ void gload_lds16(const void* g, void* lds) {
    __builtin_amdgcn_global_load_lds(
        (const __attribute__((address_space(1))) void*)g,
        (__attribute__((address_space(3))) void*)lds, 16, 0, 0);
}

__global__ __launch_bounds__(256) void convert_w(
    const float* __restrict__ src, short* __restrict__ dst, int n)
{
    for (int i = blockIdx.x * 256 + threadIdx.x; i < n; i += gridDim.x * 256)
        dst[i] = f2bf(src[i]);
}

// Y_bf16[row, d] = bf16( sum_k X[row,k]*W[d,k] + bias[d] );  K = DT_ = 256.
__global__ __launch_bounds__(512, 2) void proj_mfma(
    const float* __restrict__ X, const short* __restrict__ Wb,
    const float* __restrict__ bias, short* __restrict__ Y)
{
    __shared__ short A_lds[64 * DT_];   // 32 KB swizzled bf16
    const int t = threadIdx.x;
    const int lane = t & 63, w = t >> 6;
    const int r16 = lane & 15, g = lane >> 4;
    const long row0 = (long)blockIdx.x * 64;

    {
        const int srow = t >> 3, sc = t & 7;
        const float4* src = (const float4*)(X + (row0 + srow) * DT_) + sc;
        float4 sv[8];
        #pragma unroll
        for (int j = 0; j < 8; ++j) sv[j] = src[8 * j];
        #pragma unroll
        for (int j = 0; j < 8; ++j) {
            short4 s;
            s.x = f2bf(sv[j].x); s.y = f2bf(sv[j].y);
            s.z = f2bf(sv[j].z); s.w = f2bf(sv[j].w);
            *(short4*)((char*)A_lds + SWZ(srow, srow * (DT_ * 2) + (sc + 8 * j) * 8)) = s;
        }
    }
    __syncthreads();

    f32x4 acc[5][4];
    #pragma unroll
    for (int ct = 0; ct < 5; ++ct)
        #pragma unroll
        for (int rt = 0; rt < 4; ++rt) acc[ct][rt] = (f32x4){0.f,0.f,0.f,0.f};

    const short* Wbase = Wb + (long)(w * 80 + r16) * DT_ + g * 8;

    bf16x8 aA[4], bA[5], aB[4], bB[5];
    #pragma unroll
    for (int rt = 0; rt < 4; ++rt) {
        const int row = rt * 16 + r16;
        aA[rt] = *(const bf16x8*)((const char*)A_lds + SWZ(row, row * (DT_ * 2) + g * 16));
    }
    #pragma unroll
    for (int ct = 0; ct < 5; ++ct) bA[ct] = *(const bf16x8*)(Wbase + ct * 16 * DT_);

    #pragma unroll
    for (int kc = 0; kc < 8; kc += 2) {
        {
            const int kn = kc + 1;
            #pragma unroll
            for (int rt = 0; rt < 4; ++rt) {
                const int row = rt * 16 + r16;
                aB[rt] = *(const bf16x8*)((const char*)A_lds +
                          SWZ(row, row * (DT_ * 2) + kn * 64 + g * 16));
            }
            #pragma unroll
            for (int ct = 0; ct < 5; ++ct)
                bB[ct] = *(const bf16x8*)(Wbase + ct * 16 * DT_ + kn * 32);
        }
        #pragma unroll
        for (int ct = 0; ct < 5; ++ct)
            #pragma unroll
            for (int rt = 0; rt < 4; ++rt)
                acc[ct][rt] = __builtin_amdgcn_mfma_f32_16x16x32_bf16(
                                  aA[rt], bA[ct], acc[ct][rt], 0, 0, 0);
        {
            const int kn = (kc + 2 < 8) ? kc + 2 : 0;
            #pragma unroll
            for (int rt = 0; rt < 4; ++rt) {
                const int row = rt * 16 + r16;
                aA[rt] = *(const bf16x8*)((const char*)A_lds +
                          SWZ(row, row * (DT_ * 2) + kn * 64 + g * 16));
            }
            #pragma unroll
            for (int ct = 0; ct < 5; ++ct)
                bA[ct] = *(const bf16x8*)(Wbase + ct * 16 * DT_ + kn * 32);
        }
        #pragma unroll
        for (int ct = 0; ct < 5; ++ct)
            #pragma unroll
            for (int rt = 0; rt < 4; ++rt)
                acc[ct][rt] = __builtin_amdgcn_mfma_f32_16x16x32_bf16(
                                  aB[rt], bB[ct], acc[ct][rt], 0, 0, 0);
    }

    #pragma unroll
    for (int ct = 0; ct < 5; ++ct) {
        const int col = w * 80 + ct * 16 + r16;
        const float bv = bias[col];
        #pragma unroll
        for (int rt = 0; rt < 4; ++rt)
            #pragma unroll
            for (int i = 0; i < 4; ++i)
                Y[(row0 + rt * 16 + g * 4 + i) * (long)D_ + col] =
                    f2bf(acc[ct][rt][i] + bv);
    }
}

// Fused attention + aggregation, one batch b per block.
__global__ __launch_bounds__(512, 2) void attn2(
    const short* __restrict__ Qb, const short* __restrict__ Kb,
    float* __restrict__ aw, float* __restrict__ out_tail)
{
    __shared__ float qn_l[N_];
    __shared__ float qw_l[N_];
    __shared__ float aggp[8][MT_ * 16];
    __shared__ float red2[2];
    const int t = threadIdx.x;
    const int lane = t & 63, w = t >> 6;
    const int wm = w & 3, hh = w >> 2;
    const int r16 = lane & 15, g = lane >> 4;
    const int b = blockIdx.x;

    if (hh == 0) {
        const short* qrow = Qb + ((long)(b * N_ + wm * 16 + r16)) * D_ + g * 160;
        float ss = 0.f;
        #pragma unroll
        for (int j = 0; j < 20; ++j) {
            bf16x8 v = *(const bf16x8*)(qrow + j * 8);
            #pragma unroll
            for (int e = 0; e < 8; ++e) { float f = bf2f(v[e]); ss += f * f; }
        }
        ss += __shfl_xor(ss, 16);
        ss += __shfl_xor(ss, 32);
        if (g == 0) qn_l[wm * 16 + r16] = ss;
    }
    __syncthreads();
    if (w == 0) {
        float v = sqrtf(qn_l[lane]);
        float mx = wave_reduce_max(v);
        float e = __expf(v - mx);
        float s = wave_reduce_sum(e);
        qw_l[lane] = e / s;
    }
    __syncthreads();

    float qwr[4];
    #pragma unroll
    for (int i = 0; i < 4; ++i) qwr[i] = qw_l[wm * 16 + g * 4 + i];

    const float inv_scale = 0.0395284707521047f;   // 1/sqrt(640)
    float aggl[MT_];
    #pragma unroll
    for (int mt = 0; mt < MT_; ++mt) aggl[mt] = 0.f;

    for (int hi = 0; hi < 5; ++hi) {
        const int h = hh * 5 + hi;
        const short* qbase = Qb + ((long)(b * N_ + wm * 16 + r16)) * D_ + h * HD_ + g * 8;
        bf16x8 a0 = *(const bf16x8*)(qbase);
        bf16x8 a1 = *(const bf16x8*)(qbase + 32);
        bf16x8 kb0[MT_], kb1[MT_];
        #pragma unroll
        for (int mt = 0; mt < MT_; ++mt) {
            const short* kbase = Kb + ((long)(b * H_ + mt * 16 + r16)) * D_ + h * HD_ + g * 8;
            kb0[mt] = *(const bf16x8*)(kbase);
            kb1[mt] = *(const bf16x8*)(kbase + 32);
        }
        f32x4 acc[MT_];
        #pragma unroll
        for (int mt = 0; mt < MT_; ++mt) {
            f32x4 z = {0.f,0.f,0.f,0.f};
            z = __builtin_amdgcn_mfma_f32_16x16x32_bf16(a0, kb0[mt], z, 0, 0, 0);
            z = __builtin_amdgcn_mfma_f32_16x16x32_bf16(a1, kb1[mt], z, 0, 0, 0);
            acc[mt] = z;
        }
        const bool tailok = (r16 < 8);
        float mx[4] = {-INFINITY, -INFINITY, -INFINITY, -INFINITY};
        #pragma unroll
        for (int mt = 0; mt < MT_; ++mt) {
            const bool valid = (mt < 12) || tailok;
            #pragma unroll
            for (int i = 0; i < 4; ++i)
                if (valid) mx[i] = fmaxf(mx[i], acc[mt][i]);
        }
        #pragma unroll
        for (int i = 0; i < 4; ++i) mx[i] = red16_max(mx[i]);
        float sum[4] = {0.f, 0.f, 0.f, 0.f};
        #pragma unroll
        for (int mt = 0; mt < MT_; ++mt) {
            const bool valid = (mt < 12) || tailok;
            #pragma unroll
            for (int i = 0; i < 4; ++i) {
                float e = valid ? __expf((acc[mt][i] - mx[i]) * inv_scale) : 0.f;
                acc[mt][i] = e;
                sum[i] += e;
            }
        }
        float fct[4];
        #pragma unroll
        for (int i = 0; i < 4; ++i) fct[i] = qwr[i] / red16_sum(sum[i]);
        #pragma unroll
        for (int mt = 0; mt < MT_; ++mt)
            aggl[mt] += acc[mt][0] * fct[0] + acc[mt][1] * fct[1]
                      + acc[mt][2] * fct[2] + acc[mt][3] * fct[3];
    }
    #pragma unroll
    for (int mt = 0; mt < MT_; ++mt) {
        aggl[mt] += __shfl_xor(aggl[mt], 16);
        aggl[mt] += __shfl_xor(aggl[mt], 32);
    }
    if (g == 0) {
        #pragma unroll
        for (int mt = 0; mt < MT_; ++mt) aggp[w][mt * 16 + r16] = aggl[mt];
    }
    __syncthreads();
    if (t < MT_ * 16) {
        float v = 0.f;
        #pragma unroll
        for (int j = 0; j < 8; ++j) v += aggp[j][t];
        aggp[0][t] = v;
    }
    __syncthreads();
    if (w == 0) {
        float v0 = aggp[0][lane], v1 = aggp[0][lane + 64], v2 = aggp[0][lane + 128];
        const bool has3 = lane < (H_ - 192);
        float v3 = has3 ? aggp[0][lane + 192] : -INFINITY;
        float mx = wave_reduce_max(fmaxf(fmaxf(v0, v1), fmaxf(v2, v3)));
        float s = __expf(v0 - mx) + __expf(v1 - mx) + __expf(v2 - mx)
                + (has3 ? __expf(v3 - mx) : 0.f);
        s = wave_reduce_sum(s);
        if (lane == 0) { red2[0] = mx; red2[1] = s; }
    }
    __syncthreads();
    if (t < H_) {
        float v = __expf(aggp[0][t] - red2[0]) / red2[1];
        aw[b * H_ + t] = v;
        out_tail[b * H_ + t] = v;
    }
}

// zgemm v2: Y[row,col] = sum_k A[row,k] * Wg[col,k]  (bf16 out).
// BM=128, BN=128, BK=64, 256 threads = 4 waves (2x2).
// Rule-21 both-sides swizzle: stage via global_load_lds with XOR'd SOURCE
// granule (linear LDS dest), read fragments at the XOR'd slot -> 2-way max
// bank aliasing (free) instead of 16-way.
// Bijective XCD remap: the 5 col-strip blocks sharing an A-panel land on
// the SAME XCD -> A-panel (327 KB) and Wg (0.82 MB) reused from XCD L2.
__global__ __launch_bounds__(256, 3) void zgemm(
    const float* __restrict__ A, const short* __restrict__ Wb,
    short* __restrict__ Z)
{
    __shared__ float A_f[128 * 64];     // 32 KB fp32, slot-swizzled
    __shared__ short B_lds[128 * 64];   // 16 KB bf16, slot-swizzled
    const int t = threadIdx.x;
    const int lane = t & 63, w = t >> 6;
    const int wm = w >> 1, wn = w & 1;
    const int r16 = lane & 15, g = lane >> 4;
    // XCD-bijective remap (gridDim.x == 1000, divisible by 8)
    const int lb = (blockIdx.x & 7) * ((int)gridDim.x >> 3) + (blockIdx.x >> 3);
    const int row0 = (lb / 5) * 128;
    const int col0 = (lb % 5) * 128;

    f32x4 acc[4][4];
    #pragma unroll
    for (int ct = 0; ct < 4; ++ct)
        #pragma unroll
        for (int rt = 0; rt < 4; ++rt) acc[ct][rt] = (f32x4){0.f,0.f,0.f,0.f};

    for (int k = 0; k < 10; ++k) {
        const int k0 = k * 64;
        // stage A: slot u=(row, j) holds SOURCE granule (j ^ (row&7))
        #pragma unroll
        for (int j = 0; j < 8; ++j) {
            const int u = t + j * 256;
            const int row = u >> 4, jj = u & 15;
            gload_lds16(A + (long)(row0 + row) * D_ + k0 + ((jj ^ (row & 7)) << 2),
                        (char*)A_f + u * 16);
        }
        // stage B: slot u=(col, j) holds SOURCE granule (j ^ (col&7))
        #pragma unroll
        for (int j = 0; j < 4; ++j) {
            const int u = t + j * 256;
            const int col = u >> 3, jj = u & 7;
            gload_lds16(Wb + (long)(col0 + col) * D_ + k0 + ((jj ^ (col & 7)) << 3),
                        (char*)B_lds + u * 16);
        }
        __syncthreads();

        #pragma unroll
        for (int kk = 0; kk < 2; ++kk) {
            bf16x8 a[4];
            #pragma unroll
            for (int rt = 0; rt < 4; ++rt) {
                const int row = wm * 64 + rt * 16 + r16;
                const int s = kk * 8 + g * 2;      // source granule (4 floats)
                float4 f0 = *(const float4*)(A_f + row * 64 + ((s ^ (row & 7)) << 2));
                float4 f1 = *(const float4*)(A_f + row * 64 + (((s + 1) ^ (row & 7)) << 2));
                bf16x8 av;
                av[0] = f2bf(f0.x); av[1] = f2bf(f0.y); av[2] = f2bf(f0.z); av[3] = f2bf(f0.w);
                av[4] = f2bf(f1.x); av[5] = f2bf(f1.y); av[6] = f2bf(f1.z); av[7] = f2bf(f1.w);
                a[rt] = av;
            }
            bf16x8 b[4];
            #pragma unroll
            for (int ct = 0; ct < 4; ++ct) {
                const int col = wn * 64 + ct * 16 + r16;
                const int sb = kk * 4 + g;         // source granule (8 shorts)
                b[ct] = *(const bf16x8*)(B_lds + col * 64 + ((sb ^ (col & 7)) << 3));
            }
            #pragma unroll
            for (int ct = 0; ct < 4; ++ct)
                #pragma unroll
                for (int rt = 0; rt < 4; ++rt)
                    acc[ct][rt] = __builtin_amdgcn_mfma_f32_16x16x32_bf16(
                                      a[rt], b[ct], acc[ct][rt], 0, 0, 0);
        }
        __syncthreads();
    }

    // write Z bf16: C/D layout col = lane&15, row = g*4 + i
    #pragma unroll
    for (int ct = 0; ct < 4; ++ct) {
        const int col = col0 + wn * 64 + ct * 16 + r16;
        #pragma unroll
        for (int rt = 0; rt < 4; ++rt)
            #pragma unroll
            for (int i = 0; i < 4; ++i)
                Z[(long)(row0 + wm * 64 + rt * 16 + g * 4 + i) * D_ + col] =
                    f2bf(acc[ct][rt][i]);
    }
}

// blendln: z = aw*y + bg; gate = sigmoid(z); o = cl*(1 + gt*(aw-1)); LN.
// One wave per row; 4 rows per 256-thread block.
__global__ __launch_bounds__(256) void blendln(
    const float* __restrict__ cl, const short* __restrict__ Z,
    const float* __restrict__ aw, const float* __restrict__ bg,
    const float* __restrict__ gamma, const float* __restrict__ beta,
    float* __restrict__ out)
{
    const int t = threadIdx.x;
    const int lane = t & 63, w = t >> 6;
    const int row = blockIdx.x * 4 + w;
    const float awr = aw[row];
    const long base = (long)row * D_;

    float o[10];
    float s = 0.f, sq = 0.f;
    #pragma unroll
    for (int i = 0; i < 10; ++i) {
        const int col = lane + 64 * i;
        const float y = bf2f(Z[base + col]);
        const float c = cl[base + col];
        const float z = awr * y + bg[col];
        const float gt = 1.f / (1.f + __expf(-z));
        const float ov = c * (1.f + gt * (awr - 1.f));
        o[i] = ov; s += ov; sq += ov * ov;
    }
    s  = wave_reduce_sum(s);
    sq = wave_reduce_sum(sq);
    const float mu  = s * (1.f / D_);
    const float var = sq * (1.f / D_) - mu * mu;
    const float ri  = 1.0f / sqrtf(var + 1e-5f);
    #pragma unroll
    for (int i = 0; i < 10; ++i) {
        const int col = lane + 64 * i;
        out[base + col] = (o[i] - mu) * ri * gamma[col] + beta[col];
    }
}

extern "C" void kernel_launch(void* const* d_in, const int* in_sizes, int n_in,
                              void* d_out, int out_size, void* d_ws, size_t ws_size,
                              hipStream_t stream) {
    const float* clicked_news   = (const float*)d_in[0];   // [B,H,D]
    const float* clicked_topics = (const float*)d_in[1];   // [B,H,Dt]
    const float* cand_topics    = (const float*)d_in[2];   // [B,N,Dt]
    const float* Wq = (const float*)d_in[3];
    const float* bq = (const float*)d_in[4];
    const float* Wk = (const float*)d_in[5];
    const float* bk = (const float*)d_in[6];
    // d_in[7], d_in[8] = Wv, bv: dead code w.r.t. outputs
    const float* Wg = (const float*)d_in[9];
    const float* bg = (const float*)d_in[10];
    const float* ln_gamma = (const float*)d_in[11];
    const float* ln_beta  = (const float*)d_in[12];

    float* out = (float*)d_out;
    float* ws  = (float*)d_ws;

    // ws layout: aw, weights, then Qb; Z (bf16, half-M) ALIASES Qb (Qb is
    // dead after attn2; zgemm/blendln run after attn2 on the same stream).
    float* aw   = ws;                                    // B*H floats
    short* Wq_b = (short*)(aw + (long)B_ * H_);          // 163,840
    short* Wk_b = Wq_b + (long)D_ * DT_;                 // 163,840
    short* Wg_b = Wk_b + (long)D_ * DT_;                 // 409,600 row-major [col][k]
    short* Qb   = Wg_b + (long)D_ * D_;                  // 10,485,760
    short* Z    = Qb;                                    // 16,384,000 (overlaps Qb+)
    // Kb (bf16) at start of d_out: read by attn2, overwritten by blendln.
    short* Kb = (short*)d_out;
    float* out_tail = out + (long)B_ * H_ * D_;          // attn_weights_agg

    convert_w<<<128, 256, 0, stream>>>(Wq, Wq_b, D_ * DT_);
    convert_w<<<128, 256, 0, stream>>>(Wk, Wk_b, D_ * DT_);
    convert_w<<<256, 256, 0, stream>>>(Wg, Wg_b, D_ * D_);

    proj_mfma<<<(B_ * N_) / 64, 512, 0, stream>>>(cand_topics, Wq_b, bq, Qb);
    proj_mfma<<<(B_ * H_) / 64, 512, 0, stream>>>(clicked_topics, Wk_b, bk, Kb);
    attn2<<<B_, 512, 0, stream>>>(Qb, Kb, aw, out_tail);

    for (int h = 0; h < 2; ++h) {
        const long off = (long)h * MH_;
        zgemm<<<(MH_ / 128) * 5, 256, 0, stream>>>(
            clicked_news + off * D_, Wg_b, Z);
        blendln<<<MH_ / 4, 256, 0, stream>>>(
            clicked_news + off * D_, Z, aw + off, bg, ln_gamma, ln_beta,
            out + off * D_);
    }
}

// Round 14
// 289.123 us; speedup vs baseline: 1.6902x; 1.0378x over previous
//
#include <hip/hip_runtime.h>
#include <math.h>

#define B_  256
#define H_  200
#define N_  64
#define D_  640
#define DT_ 256
#define NH_ 10
#define HD_ 64
#define MT_ 13   // 13 m-tiles of 16 cover 208 >= 200
#define MH_ 25600  // M half (B_*H_/2)

typedef __attribute__((ext_vector_type(8))) short bf16x8;
typedef __attribute__((ext_vector_type(4))) float f32x4;

__device__ __forceinline__ float wave_reduce_sum(float v) {
    #pragma unroll
    for (int m = 32; m > 0; m >>= 1) v += __shfl_xor(v, m);
    return v;
}
__device__ __forceinline__ float wave_reduce_max(float v) {
    #pragma unroll
    for (int m = 32; m > 0; m >>= 1) v = fmaxf(v, __shfl_xor(v, m));
    return v;
}
__device__ __forceinline__ float red16_sum(float v) {   // reduce over lane&15 group
    #pragma unroll
    for (int m = 1; m < 16; m <<= 1) v += __shfl_xor(v, m);
    return v;
}
__device__ __forceinline__ float red16_max(float v) {
    #pragma unroll
    for (int m = 1; m < 16; m <<= 1) v = fmaxf(v, __shfl_xor(v, m));
    return v;
}
__device__ __forceinline__ short f2bf(float x) {   // RNE bf16
    unsigned u = __float_as_uint(x);
    unsigned r = (u + 0x7fffu + ((u >> 16) & 1u)) >> 16;
    return (short)r;
}
__device__ __forceinline__ float bf2f(short s) {
    return __uint_as_float(((unsigned)(unsigned short)s) << 16);
}

__device__ __forceinline__ void gload_lds16(const void* g, void* lds) {
    __builtin_amdgcn_global_load_lds(
        (const __attribute__((address_space(1))) void*)g,
        (__attribute__((address_space(3))) void*)lds, 16, 0, 0);
}

__global__ __launch_bounds__(256) void convert_w(
    const float* __restrict__ src, short* __restrict__ dst, int n)
{
    for (int i = blockIdx.x * 256 + threadIdx.x; i < n; i += gridDim.x * 256)
        dst[i] = f2bf(src[i]);
}

// gemm_bt: Y_bf16[row,col] = bf16( sum_k A[row,k]*W[col,k] (+ bias[col]) ).
// A fp32 [M][lda], W bf16 [640][ldb], Y bf16 [M][640].
// BM=128, BN=128, BK=64, 256 threads = 4 waves (2x2), acc[4][4].
// Both operands staged via global_load_lds with rule-21 both-sides swizzle
// (XOR'd SOURCE granule -> linear LDS -> XOR'd read): 2-way max bank alias.
// Bijective XCD remap (grid % 8 == 0): the 5 col-strips sharing an A-panel
// land on one XCD -> A-panel + full W reused from that XCD's L2.
__global__ __launch_bounds__(256, 3) void gemm_bt(
    const float* __restrict__ A, int lda,
    const short* __restrict__ Wb, int ldb,
    const float* __restrict__ bias,
    short* __restrict__ Y, int nkc)
{
    __shared__ float A_f[128 * 64];     // 32 KB fp32, slot-swizzled
    __shared__ short B_lds[128 * 64];   // 16 KB bf16, slot-swizzled
    const int t = threadIdx.x;
    const int lane = t & 63, w = t >> 6;
    const int wm = w >> 1, wn = w & 1;
    const int r16 = lane & 15, g = lane >> 4;
    const int lb = (blockIdx.x & 7) * ((int)gridDim.x >> 3) + (blockIdx.x >> 3);
    const int row0 = (lb / 5) * 128;
    const int col0 = (lb % 5) * 128;

    f32x4 acc[4][4];
    #pragma unroll
    for (int ct = 0; ct < 4; ++ct)
        #pragma unroll
        for (int rt = 0; rt < 4; ++rt) acc[ct][rt] = (f32x4){0.f,0.f,0.f,0.f};

    for (int k = 0; k < nkc; ++k) {
        const int k0 = k * 64;
        // stage A: slot u=(row, j) holds SOURCE granule (j ^ (row&7))
        #pragma unroll
        for (int j = 0; j < 8; ++j) {
            const int u = t + j * 256;
            const int row = u >> 4, jj = u & 15;
            gload_lds16(A + (long)(row0 + row) * lda + k0 + ((jj ^ (row & 7)) << 2),
                        (char*)A_f + u * 16);
        }
        // stage B: slot u=(col, j) holds SOURCE granule (j ^ (col&7))
        #pragma unroll
        for (int j = 0; j < 4; ++j) {
            const int u = t + j * 256;
            const int col = u >> 3, jj = u & 7;
            gload_lds16(Wb + (long)(col0 + col) * ldb + k0 + ((jj ^ (col & 7)) << 3),
                        (char*)B_lds + u * 16);
        }
        __syncthreads();

        #pragma unroll
        for (int kk = 0; kk < 2; ++kk) {
            bf16x8 a[4];
            #pragma unroll
            for (int rt = 0; rt < 4; ++rt) {
                const int row = wm * 64 + rt * 16 + r16;
                const int s = kk * 8 + g * 2;      // source granule (4 floats)
                float4 f0 = *(const float4*)(A_f + row * 64 + ((s ^ (row & 7)) << 2));
                float4 f1 = *(const float4*)(A_f + row * 64 + (((s + 1) ^ (row & 7)) << 2));
                bf16x8 av;
                av[0] = f2bf(f0.x); av[1] = f2bf(f0.y); av[2] = f2bf(f0.z); av[3] = f2bf(f0.w);
                av[4] = f2bf(f1.x); av[5] = f2bf(f1.y); av[6] = f2bf(f1.z); av[7] = f2bf(f1.w);
                a[rt] = av;
            }
            bf16x8 b[4];
            #pragma unroll
            for (int ct = 0; ct < 4; ++ct) {
                const int col = wn * 64 + ct * 16 + r16;
                const int sb = kk * 4 + g;         // source granule (8 shorts)
                b[ct] = *(const bf16x8*)(B_lds + col * 64 + ((sb ^ (col & 7)) << 3));
            }
            #pragma unroll
            for (int ct = 0; ct < 4; ++ct)
                #pragma unroll
                for (int rt = 0; rt < 4; ++rt)
                    acc[ct][rt] = __builtin_amdgcn_mfma_f32_16x16x32_bf16(
                                      a[rt], b[ct], acc[ct][rt], 0, 0, 0);
        }
        __syncthreads();
    }

    // write Y bf16: C/D layout col = lane&15, row = g*4 + i
    #pragma unroll
    for (int ct = 0; ct < 4; ++ct) {
        const int col = col0 + wn * 64 + ct * 16 + r16;
        const float bv = bias ? bias[col] : 0.f;
        #pragma unroll
        for (int rt = 0; rt < 4; ++rt)
            #pragma unroll
            for (int i = 0; i < 4; ++i)
                Y[(long)(row0 + wm * 64 + rt * 16 + g * 4 + i) * D_ + col] =
                    f2bf(acc[ct][rt][i] + bv);
    }
}

// Fused attention + aggregation, one batch b per block.
__global__ __launch_bounds__(512, 2) void attn2(
    const short* __restrict__ Qb, const short* __restrict__ Kb,
    float* __restrict__ aw, float* __restrict__ out_tail)
{
    __shared__ float qn_l[N_];
    __shared__ float qw_l[N_];
    __shared__ float aggp[8][MT_ * 16];
    __shared__ float red2[2];
    const int t = threadIdx.x;
    const int lane = t & 63, w = t >> 6;
    const int wm = w & 3, hh = w >> 2;
    const int r16 = lane & 15, g = lane >> 4;
    const int b = blockIdx.x;

    if (hh == 0) {
        const short* qrow = Qb + ((long)(b * N_ + wm * 16 + r16)) * D_ + g * 160;
        float ss = 0.f;
        #pragma unroll
        for (int j = 0; j < 20; ++j) {
            bf16x8 v = *(const bf16x8*)(qrow + j * 8);
            #pragma unroll
            for (int e = 0; e < 8; ++e) { float f = bf2f(v[e]); ss += f * f; }
        }
        ss += __shfl_xor(ss, 16);
        ss += __shfl_xor(ss, 32);
        if (g == 0) qn_l[wm * 16 + r16] = ss;
    }
    __syncthreads();
    if (w == 0) {
        float v = sqrtf(qn_l[lane]);
        float mx = wave_reduce_max(v);
        float e = __expf(v - mx);
        float s = wave_reduce_sum(e);
        qw_l[lane] = e / s;
    }
    __syncthreads();

    float qwr[4];
    #pragma unroll
    for (int i = 0; i < 4; ++i) qwr[i] = qw_l[wm * 16 + g * 4 + i];

    const float inv_scale = 0.0395284707521047f;   // 1/sqrt(640)
    float aggl[MT_];
    #pragma unroll
    for (int mt = 0; mt < MT_; ++mt) aggl[mt] = 0.f;

    for (int hi = 0; hi < 5; ++hi) {
        const int h = hh * 5 + hi;
        const short* qbase = Qb + ((long)(b * N_ + wm * 16 + r16)) * D_ + h * HD_ + g * 8;
        bf16x8 a0 = *(const bf16x8*)(qbase);
        bf16x8 a1 = *(const bf16x8*)(qbase + 32);
        bf16x8 kb0[MT_], kb1[MT_];
        #pragma unroll
        for (int mt = 0; mt < MT_; ++mt) {
            const short* kbase = Kb + ((long)(b * H_ + mt * 16 + r16)) * D_ + h * HD_ + g * 8;
            kb0[mt] = *(const bf16x8*)(kbase);
            kb1[mt] = *(const bf16x8*)(kbase + 32);
        }
        f32x4 acc[MT_];
        #pragma unroll
        for (int mt = 0; mt < MT_; ++mt) {
            f32x4 z = {0.f,0.f,0.f,0.f};
            z = __builtin_amdgcn_mfma_f32_16x16x32_bf16(a0, kb0[mt], z, 0, 0, 0);
            z = __builtin_amdgcn_mfma_f32_16x16x32_bf16(a1, kb1[mt], z, 0, 0, 0);
            acc[mt] = z;
        }
        const bool tailok = (r16 < 8);
        float mx[4] = {-INFINITY, -INFINITY, -INFINITY, -INFINITY};
        #pragma unroll
        for (int mt = 0; mt < MT_; ++mt) {
            const bool valid = (mt < 12) || tailok;
            #pragma unroll
            for (int i = 0; i < 4; ++i)
                if (valid) mx[i] = fmaxf(mx[i], acc[mt][i]);
        }
        #pragma unroll
        for (int i = 0; i < 4; ++i) mx[i] = red16_max(mx[i]);
        float sum[4] = {0.f, 0.f, 0.f, 0.f};
        #pragma unroll
        for (int mt = 0; mt < MT_; ++mt) {
            const bool valid = (mt < 12) || tailok;
            #pragma unroll
            for (int i = 0; i < 4; ++i) {
                float e = valid ? __expf((acc[mt][i] - mx[i]) * inv_scale) : 0.f;
                acc[mt][i] = e;
                sum[i] += e;
            }
        }
        float fct[4];
        #pragma unroll
        for (int i = 0; i < 4; ++i) fct[i] = qwr[i] / red16_sum(sum[i]);
        #pragma unroll
        for (int mt = 0; mt < MT_; ++mt)
            aggl[mt] += acc[mt][0] * fct[0] + acc[mt][1] * fct[1]
                      + acc[mt][2] * fct[2] + acc[mt][3] * fct[3];
    }
    #pragma unroll
    for (int mt = 0; mt < MT_; ++mt) {
        aggl[mt] += __shfl_xor(aggl[mt], 16);
        aggl[mt] += __shfl_xor(aggl[mt], 32);
    }
    if (g == 0) {
        #pragma unroll
        for (int mt = 0; mt < MT_; ++mt) aggp[w][mt * 16 + r16] = aggl[mt];
    }
    __syncthreads();
    if (t < MT_ * 16) {
        float v = 0.f;
        #pragma unroll
        for (int j = 0; j < 8; ++j) v += aggp[j][t];
        aggp[0][t] = v;
    }
    __syncthreads();
    if (w == 0) {
        float v0 = aggp[0][lane], v1 = aggp[0][lane + 64], v2 = aggp[0][lane + 128];
        const bool has3 = lane < (H_ - 192);
        float v3 = has3 ? aggp[0][lane + 192] : -INFINITY;
        float mx = wave_reduce_max(fmaxf(fmaxf(v0, v1), fmaxf(v2, v3)));
        float s = __expf(v0 - mx) + __expf(v1 - mx) + __expf(v2 - mx)
                + (has3 ? __expf(v3 - mx) : 0.f);
        s = wave_reduce_sum(s);
        if (lane == 0) { red2[0] = mx; red2[1] = s; }
    }
    __syncthreads();
    if (t < H_) {
        float v = __expf(aggp[0][t] - red2[0]) / red2[1];
        aw[b * H_ + t] = v;
        out_tail[b * H_ + t] = v;
    }
}

// blendln: z = aw*y + bg; gate = sigmoid(z); o = cl*(1 + gt*(aw-1)); LN.
// One wave per row; 4 rows per 256-thread block.
__global__ __launch_bounds__(256) void blendln(
    const float* __restrict__ cl, const short* __restrict__ Z,
    const float* __restrict__ aw, const float* __restrict__ bg,
    const float* __restrict__ gamma, const float* __restrict__ beta,
    float* __restrict__ out)
{
    const int t = threadIdx.x;
    const int lane = t & 63, w = t >> 6;
    const int row = blockIdx.x * 4 + w;
    const float awr = aw[row];
    const long base = (long)row * D_;

    float o[10];
    float s = 0.f, sq = 0.f;
    #pragma unroll
    for (int i = 0; i < 10; ++i) {
        const int col = lane + 64 * i;
        const float y = bf2f(Z[base + col]);
        const float c = cl[base + col];
        const float z = awr * y + bg[col];
        const float gt = 1.f / (1.f + __expf(-z));
        const float ov = c * (1.f + gt * (awr - 1.f));
        o[i] = ov; s += ov; sq += ov * ov;
    }
    s  = wave_reduce_sum(s);
    sq = wave_reduce_sum(sq);
    const float mu  = s * (1.f / D_);
    const float var = sq * (1.f / D_) - mu * mu;
    const float ri  = 1.0f / sqrtf(var + 1e-5f);
    #pragma unroll
    for (int i = 0; i < 10; ++i) {
        const int col = lane + 64 * i;
        out[base + col] = (o[i] - mu) * ri * gamma[col] + beta[col];
    }
}

extern "C" void kernel_launch(void* const* d_in, const int* in_sizes, int n_in,
                              void* d_out, int out_size, void* d_ws, size_t ws_size,
                              hipStream_t stream) {
    const float* clicked_news   = (const float*)d_in[0];   // [B,H,D]
    const float* clicked_topics = (const float*)d_in[1];   // [B,H,Dt]
    const float* cand_topics    = (const float*)d_in[2];   // [B,N,Dt]
    const float* Wq = (const float*)d_in[3];
    const float* bq = (const float*)d_in[4];
    const float* Wk = (const float*)d_in[5];
    const float* bk = (const float*)d_in[6];
    // d_in[7], d_in[8] = Wv, bv: dead code w.r.t. outputs
    const float* Wg = (const float*)d_in[9];
    const float* bg = (const float*)d_in[10];
    const float* ln_gamma = (const float*)d_in[11];
    const float* ln_beta  = (const float*)d_in[12];

    float* out = (float*)d_out;
    float* ws  = (float*)d_ws;

    // ws layout: aw, weights, then Qb; Z (bf16, half-M) ALIASES Qb (Qb is
    // dead after attn2; gemm/blendln run after attn2 on the same stream).
    float* aw   = ws;                                    // B*H floats
    short* Wq_b = (short*)(aw + (long)B_ * H_);          // 163,840
    short* Wk_b = Wq_b + (long)D_ * DT_;                 // 163,840
    short* Wg_b = Wk_b + (long)D_ * DT_;                 // 409,600 row-major [col][k]
    short* Qb   = Wg_b + (long)D_ * D_;                  // 10,485,760
    short* Z    = Qb;                                    // 16,384,000 (overlaps Qb+)
    // Kb (bf16) at start of d_out: read by attn2, overwritten by blendln.
    short* Kb = (short*)d_out;
    float* out_tail = out + (long)B_ * H_ * D_;          // attn_weights_agg

    convert_w<<<128, 256, 0, stream>>>(Wq, Wq_b, D_ * DT_);
    convert_w<<<128, 256, 0, stream>>>(Wk, Wk_b, D_ * DT_);
    convert_w<<<256, 256, 0, stream>>>(Wg, Wg_b, D_ * D_);

    // Q-proj: M=16384 -> 128 row-panels x 5 col-strips = 640 blocks (÷8 ok)
    gemm_bt<<<640, 256, 0, stream>>>(cand_topics, DT_, Wq_b, DT_, bq, Qb, 4);
    // K-proj: M=51200 -> 400 x 5 = 2000 blocks (÷8 ok)
    gemm_bt<<<2000, 256, 0, stream>>>(clicked_topics, DT_, Wk_b, DT_, bk, Kb, 4);
    attn2<<<B_, 512, 0, stream>>>(Qb, Kb, aw, out_tail);

    for (int h = 0; h < 2; ++h) {
        const long off = (long)h * MH_;
        // gate GEMM half: M=25600 -> 200 x 5 = 1000 blocks (÷8 ok)
        gemm_bt<<<1000, 256, 0, stream>>>(clicked_news + off * D_, D_,
                                          Wg_b, D_, nullptr, Z, 10);
        blendln<<<MH_ / 4, 256, 0, stream>>>(
            clicked_news + off * D_, Z, aw + off, bg, ln_gamma, ln_beta,
            out + off * D_);
    }
}